// Round 8
// baseline (180.009 us; speedup 1.0000x reference)
//
#include <hip/hip_runtime.h>
#include <math.h>

// Analytic inverse of [[R, t],[0,0,0,1]] where R comes from a normalized quat:
// inv = [[R^T, -R^T t],[0,0,0,1]].
struct Inv {
    float i00, i01, i02, it0;
    float i10, i11, i12, it1;
    float i20, i21, i22, it2;
};

__device__ __forceinline__ Inv make_inv(const float* __restrict__ q,
                                        const float* __restrict__ t, int b) {
    float w = q[b * 4 + 0], x = q[b * 4 + 1], y = q[b * 4 + 2], z = q[b * 4 + 3];
    float inv_n = 1.0f / sqrtf(w * w + x * x + y * y + z * z);
    w *= inv_n; x *= inv_n; y *= inv_n; z *= inv_n;
    float R00 = 1.f - 2.f * y * y - 2.f * z * z;
    float R01 = 2.f * x * y - 2.f * z * w;
    float R02 = 2.f * x * z + 2.f * y * w;
    float R10 = 2.f * x * y + 2.f * z * w;
    float R11 = 1.f - 2.f * x * x - 2.f * z * z;
    float R12 = 2.f * y * z - 2.f * x * w;
    float R20 = 2.f * x * z - 2.f * y * w;
    float R21 = 2.f * y * z + 2.f * x * w;
    float R22 = 1.f - 2.f * x * x - 2.f * y * y;
    float t0 = t[b * 3 + 0], t1 = t[b * 3 + 1], t2 = t[b * 3 + 2];
    Inv v;
    v.i00 = R00; v.i01 = R10; v.i02 = R20; v.it0 = -(R00 * t0 + R10 * t1 + R20 * t2);
    v.i10 = R01; v.i11 = R11; v.i12 = R21; v.it1 = -(R01 * t0 + R11 * t1 + R21 * t2);
    v.i20 = R02; v.i21 = R12; v.i22 = R22; v.it2 = -(R02 * t0 + R12 * t1 + R22 * t2);
    return v;
}

__device__ __forceinline__ void xf(const Inv& M, float px, float py, float pz,
                                   float& ox, float& oy, float& oz) {
    ox = fmaf(M.i00, px, fmaf(M.i01, py, fmaf(M.i02, pz, M.it0)));
    oy = fmaf(M.i10, px, fmaf(M.i11, py, fmaf(M.i12, pz, M.it1)));
    oz = fmaf(M.i20, px, fmaf(M.i21, py, fmaf(M.i22, pz, M.it2)));
}

using nat_f4 = __attribute__((ext_vector_type(4))) float;
// NT load — KEPT (R6 win: bypasses L3 retention; harness fills flush L3 with
// ~800 MB/replay so the input can never stay resident. NT turns the
// half-hit/half-miss read interleave into a clean full HBM stream).
__device__ __forceinline__ float4 load_nt(const float4* p) {
    nat_f4 v = __builtin_nontemporal_load((const nat_f4*)p);
    float4 r; *(nat_f4*)&r = v; return r;
}

// ROUND 8 — clean structural experiment: phase-aware streaming, zero LDS,
// zero barriers, BOTH streams perfectly coalesced with unique coverage.
//
// Ledger: R0/R1/R4 (LDS+barriers, cached reads) = 2.5 TB/s wall. R6 (NT
// loads) -> ~3.5 TB/s. R7 (cached stores) neutral. Comparators on the same
// part: fill 6.7 TB/s, copy 6.3 TB/s. R5's "no-LDS" test was confounded
// (cached reads + strided NT stores caused +30% WRITE amplification), so
// the barrier-phase structure has never been cleanly tested in the
// clean-read regime. This kernel is that test: each thread owns ONE output
// float4 (aligned, coalesced store) and ONE input float4 (aligned,
// coalesced NT load). The 4 out-of-range words a thread needs (the 3-float
// point structure straddles float4 boundaries) come from delta-1 lane
// shuffles; wave-edge lanes do a tiny masked scalar fixup load (<=6% read
// overhead). phi = w%3 picks one of three 12-FMA component layouts.
// Copy-shaped schedule: load -> shuffle -> FMA -> store, nothing else.
__global__ __launch_bounds__(256) void realign_phase_kernel(
        const float4* __restrict__ pcd,
        const float* __restrict__ T_mis,
        const float* __restrict__ q,
        const float* __restrict__ t,
        float* __restrict__ out_mat,
        float4* __restrict__ out_pcd,
        int f4_per_batch, int total_f4) {
    const int w    = blockIdx.x * 256 + threadIdx.x;   // output float4 index
    const int lane = threadIdx.x & 63;

    // Words W..W+3 where W = 4w (16B-aligned unique coverage).
    const float4 A = load_nt(&pcd[w]);

    // Neighbor words via delta-1 shuffles:
    //   lom2/lom1 = words W-2, W-1 (lane-1's A.z, A.w)
    //   hi4 /hi5  = words W+4, W+5 (lane+1's A.x, A.y)
    float lom2 = __shfl_up(A.z, 1);
    float lom1 = __shfl_up(A.w, 1);
    float hi4  = __shfl_down(A.x, 1);
    float hi5  = __shfl_down(A.y, 1);

    // Wave-edge fixups (masked; ~2 scalar loads per wave).
    const float* pf = (const float*)pcd;
    if (lane == 0 && w > 0) {
        lom2 = pf[4 * w - 2];
        lom1 = pf[4 * w - 1];
    }
    if (lane == 63 && w + 1 < total_f4) {
        hi4 = pf[4 * w + 4];
        hi5 = pf[4 * w + 5];
    }
    // Global edges: w==0 has phi=0 (doesn't use lom*); w==total_f4-1 has
    // phi=2 (doesn't use hi*). Total words = 3*npoints, batch size % 64 == 0.

    // Batch index: wave-uniform (f4_per_batch % 64 == 0, consecutive w per
    // wave) -> readfirstlane lets q/t loads scalarize.
    const int wb = __builtin_amdgcn_readfirstlane(w);
    const int b  = wb / f4_per_batch;
    const Inv M  = make_inv(q, t, b);

    // Fused tmat: batch_T_pred = inv_T @ T_mis, 512 elements spread over the
    // first two blocks (one element per thread; bb lane-varying is fine).
    if (w < 512) {
        const int bb = w >> 4;
        const int i  = (w >> 2) & 3;
        const int j  = w & 3;
        const Inv Mb = make_inv(q, t, bb);
        const float* Tb = T_mis + bb * 16;
        float val;
        if (i < 3) {
            float a0, a1, a2, itr;
            if (i == 0)      { a0 = Mb.i00; a1 = Mb.i01; a2 = Mb.i02; itr = Mb.it0; }
            else if (i == 1) { a0 = Mb.i10; a1 = Mb.i11; a2 = Mb.i12; itr = Mb.it1; }
            else             { a0 = Mb.i20; a1 = Mb.i21; a2 = Mb.i22; itr = Mb.it2; }
            val = fmaf(a0, Tb[0 * 4 + j],
                  fmaf(a1, Tb[1 * 4 + j],
                  fmaf(a2, Tb[2 * 4 + j],
                       itr * Tb[3 * 4 + j])));
        } else {
            val = Tb[3 * 4 + j];
        }
        out_mat[w] = val;
    }

    // Component phase of word W = 4w:  phi = (4w) mod 3 = w mod 3.
    //   phi=0: out = [X(p0) Y(p0) Z(p0) X(p1)], p0=(A.x,A.y,A.z) p1=(A.w,hi4,hi5)
    //   phi=1: out = [Y(p0) Z(p0) X(p1) Y(p1)], p0=(lom1,A.x,A.y) p1=(A.z,A.w,hi4)
    //   phi=2: out = [Z(p0) X(p1) Y(p1) Z(p1)], p0=(lom2,lom1,A.x) p1=(A.y,A.z,A.w)
    const int phi = w % 3;
    float4 o;
    if (phi == 0) {
        xf(M, A.x, A.y, A.z, o.x, o.y, o.z);
        o.w = fmaf(M.i00, A.w, fmaf(M.i01, hi4, fmaf(M.i02, hi5, M.it0)));
    } else if (phi == 1) {
        o.x = fmaf(M.i10, lom1, fmaf(M.i11, A.x, fmaf(M.i12, A.y, M.it1)));
        o.y = fmaf(M.i20, lom1, fmaf(M.i21, A.x, fmaf(M.i22, A.y, M.it2)));
        o.z = fmaf(M.i00, A.z,  fmaf(M.i01, A.w, fmaf(M.i02, hi4, M.it0)));
        o.w = fmaf(M.i10, A.z,  fmaf(M.i11, A.w, fmaf(M.i12, hi4, M.it1)));
    } else {
        o.x = fmaf(M.i20, lom2, fmaf(M.i21, lom1, fmaf(M.i22, A.x, M.it2)));
        xf(M, A.y, A.z, A.w, o.y, o.z, o.w);
    }

    out_pcd[w] = o;   // cached store (policy proven neutral R4/R7), coalesced
}

extern "C" void kernel_launch(void* const* d_in, const int* in_sizes, int n_in,
                              void* d_out, int out_size, void* d_ws, size_t ws_size,
                              hipStream_t stream) {
    const float* pcd   = (const float*)d_in[0];  // (B, N, 3)
    const float* T_mis = (const float*)d_in[1];  // (B, 4, 4)
    const float* q     = (const float*)d_in[2];  // (B, 4)
    const float* t     = (const float*)d_in[3];  // (B, 3)
    float* out = (float*)d_out;

    const int B = in_sizes[2] / 4;                            // 32
    const long long N = (long long)in_sizes[0] / (3LL * B);   // 262144
    const int f4_per_batch = (int)(3 * N / 4);                // 196608 (%64==0)
    const int total_f4 = f4_per_batch * B;                    // 6291456
    const int blocks = total_f4 / 256;                        // 24576 (exact)

    // Output layout: [0, B*16) = batch_T_pred; then pcd_new (float4-aligned).
    realign_phase_kernel<<<dim3(blocks), 256, 0, stream>>>(
        (const float4*)pcd, T_mis, q, t,
        out, (float4*)(out + B * 16), f4_per_batch, total_f4);
}